// Round 15
// baseline (107.696 us; speedup 1.0000x reference)
//
#include <hip/hip_runtime.h>
#include <hip/hip_bf16.h>
#include <hip/hip_fp8.h>

#define HALF 4096
#define NTOT 8192
#define D 128
#define KS2 3.79828256f   // sqrt(10*log2(e)); acc = s_ij*log2(e), e = exp2(acc)

typedef __attribute__((ext_vector_type(4))) float f32x4;

__device__ __forceinline__ float wave_sum64(float v) {
#pragma unroll
    for (int m = 32; m >= 1; m >>= 1) v += __shfl_xor(v, m);
    return v;
}

// One wave per pair b. Writes x*KS2 as fp8 e4m3 in MFMA-fragment-packed layout:
// byte offset g*2048 + k*512 + (quad*16+lrow)*8 + j <-> X[g*16+lrow][k*32+quad*8+j]
// (R11-proven). Also: spos[b] (exact fp32 positive dot), sii2[row] = log2-scaled
// self-sim from the SAME fp8-rounded values (exact diagonal cancellation), and
// zero-init of the acc/done counters used by rowterm.
__global__ void cast_pos_kernel(const float* __restrict__ f1, const float* __restrict__ f2,
                                unsigned char* __restrict__ xs, float* __restrict__ spos,
                                float* __restrict__ sii2, float* __restrict__ acc,
                                unsigned int* __restrict__ done) {
    if (blockIdx.x == 0 && threadIdx.x == 0) { *acc = 0.f; *done = 0u; }

    int w = (blockIdx.x * blockDim.x + threadIdx.x) >> 6;   // pair index b, 0..4095
    int l = threadIdx.x & 63;
    float2 a1 = ((const float2*)(f1 + (size_t)w * D))[l];
    float2 a2 = ((const float2*)(f2 + (size_t)w * D))[l];

    __hip_fp8_e4m3 q1x(a1.x * KS2), q1y(a1.y * KS2);
    __hip_fp8_e4m3 q2x(a2.x * KS2), q2y(a2.y * KS2);

    // this thread covers X[w][2l..2l+2): k = l>>4, quad = (l>>2)&3, j = (l&3)*2
    int g = w >> 4, lrow = w & 15;
    int k = l >> 4, quad = (l >> 2) & 3, j = (l & 3) * 2;
    size_t off = (size_t)g * 2048 + k * 512 + (quad * 16 + lrow) * 8 + j;
    *(unsigned short*)(xs + off) =
        (unsigned short)(q1x.__x | ((unsigned short)q1y.__x << 8));
    *(unsigned short*)(xs + off + 256 * 2048) =
        (unsigned short)(q2x.__x | ((unsigned short)q2y.__x << 8));

    // self-sim from the SAME fp8-rounded values (cancels vs MFMA diagonal)
    float b1x = (float)q1x, b1y = (float)q1y;
    float b2x = (float)q2x, b2y = (float)q2y;
    float s1 = b1x * b1x + b1y * b1y;
    float s2 = b2x * b2x + b2y * b2y;
    float d  = a1.x * a2.x + a1.y * a2.y;
    s1 = wave_sum64(s1); s2 = wave_sum64(s2); d = wave_sum64(d);
    if (l == 0) {
        sii2[w] = s1; sii2[w + HALF] = s2;
        float sp = d * 10.0f;
        spos[w] = sp; spos[w + HALF] = sp;
    }
}

// LDS-free, fence-free, atomic-free Gram row-sum sweep on packed fp8 operands
// (1 MB -> L2-resident). Grid 1024 = 8 slabs x 128 panels = exactly 4
// blocks/CU, single perfectly-balanced round. Block: rows panel*64..+63,
// cols slab*1024..+1023 over 8 tile-steps; wave = 64 rows x 32 cols/step.
// R15: two-buffer rotation written the R12 way (plain local arrays, loads
// in-line in the loop body — R14's template/reference version spilled):
// unroll-by-2 rolled loop; each half consumes its buffer with 32 MFMAs,
// immediately reloads that buffer with tile+2 (~1.5 steps / ~700 cy of
// latency cover), then runs the exp2 row-sum block. ~124 unified regs
// (92 arch + 32 acc), fits the 128-reg cap at 4/CU. Outer loop stays rolled
// (full unroll => spill, R5). Plain disjoint-slot stores (R11: fences/atomics
// in the gram tail poison L2).
__global__ __launch_bounds__(256, 4) void gram_kernel(const unsigned char* __restrict__ xs,
                                                      float* __restrict__ E1p) {
    const int slab = blockIdx.x;    // 0..7
    const int panel = blockIdx.y;   // 0..127
    const int t = threadIdx.x;
    const int wave = t >> 6, lane = t & 63;
    const int lrow = lane & 15, quad = lane >> 4;

    // A fragments: row group g = panel*4 + r; byte off g*2048 + k*512 + lane*8
    const unsigned char* ab = xs + (size_t)panel * 4 * 2048 + lane * 8;
    long af[4][4];
#pragma unroll
    for (int k = 0; k < 4; ++k)
#pragma unroll
        for (int r = 0; r < 4; ++r)
            af[k][r] = *(const long*)(ab + r * 2048 + k * 512);

    // B base: col group = slab*64 + tt*8 + wave*2 + c (2048 B per group)
    const unsigned char* bb = xs + ((size_t)slab * 64 + wave * 2) * 2048 + lane * 8;
    long bf0[4][2], bf1[4][2];
#pragma unroll
    for (int k = 0; k < 4; ++k)
#pragma unroll
        for (int c = 0; c < 2; ++c) {
            bf0[k][c] = *(const long*)(bb + c * 2048 + k * 512);            // tile 0
            bf1[k][c] = *(const long*)(bb + 16384 + c * 2048 + k * 512);    // tile 1
        }

    f32x4 rs4[4];
#pragma unroll
    for (int r = 0; r < 4; ++r) rs4[r] = (f32x4){0.f, 0.f, 0.f, 0.f};

#pragma unroll 1
    for (int it = 0; it < 4; ++it) {
        // ---- half A: consume bf0 (tile 2it), reload bf0 <- tile 2it+2 ----
        {
            f32x4 a2[4][2];
#pragma unroll
            for (int r = 0; r < 4; ++r)
#pragma unroll
                for (int c = 0; c < 2; ++c) a2[r][c] = (f32x4){0.f, 0.f, 0.f, 0.f};
#pragma unroll
            for (int k = 0; k < 4; ++k)
#pragma unroll
                for (int r = 0; r < 4; ++r)
#pragma unroll
                    for (int c = 0; c < 2; ++c)
                        a2[r][c] = __builtin_amdgcn_mfma_f32_16x16x32_fp8_fp8(af[k][r], bf0[k][c], a2[r][c], 0, 0, 0);
            if (it < 3) {
                const unsigned char* bn = bb + (size_t)(2 * it + 2) * 16384;
#pragma unroll
                for (int k = 0; k < 4; ++k)
#pragma unroll
                    for (int c = 0; c < 2; ++c)
                        bf0[k][c] = *(const long*)(bn + c * 2048 + k * 512);
            }
#pragma unroll
            for (int r = 0; r < 4; ++r)
#pragma unroll
                for (int c = 0; c < 2; ++c)
#pragma unroll
                    for (int g = 0; g < 4; ++g)
                        rs4[r][g] += __builtin_amdgcn_exp2f(a2[r][c][g]);
        }
        // ---- half B: consume bf1 (tile 2it+1), reload bf1 <- tile 2it+3 ----
        {
            f32x4 a2[4][2];
#pragma unroll
            for (int r = 0; r < 4; ++r)
#pragma unroll
                for (int c = 0; c < 2; ++c) a2[r][c] = (f32x4){0.f, 0.f, 0.f, 0.f};
#pragma unroll
            for (int k = 0; k < 4; ++k)
#pragma unroll
                for (int r = 0; r < 4; ++r)
#pragma unroll
                    for (int c = 0; c < 2; ++c)
                        a2[r][c] = __builtin_amdgcn_mfma_f32_16x16x32_fp8_fp8(af[k][r], bf1[k][c], a2[r][c], 0, 0, 0);
            if (it < 3) {
                const unsigned char* bn = bb + (size_t)(2 * it + 3) * 16384;
#pragma unroll
                for (int k = 0; k < 4; ++k)
#pragma unroll
                    for (int c = 0; c < 2; ++c)
                        bf1[k][c] = *(const long*)(bn + c * 2048 + k * 512);
            }
#pragma unroll
            for (int r = 0; r < 4; ++r)
#pragma unroll
                for (int c = 0; c < 2; ++c)
#pragma unroll
                    for (int g = 0; g < 4; ++g)
                        rs4[r][g] += __builtin_amdgcn_exp2f(a2[r][c][g]);
        }
    }

    // reduce over the 16 lanes sharing a quad; disjoint-slot store (no atomics)
    const int slot = slab * 4 + wave;   // 0..31
#pragma unroll
    for (int r = 0; r < 4; ++r) {
#pragma unroll
        for (int g = 0; g < 4; ++g) {
            float v = rs4[r][g];
#pragma unroll
            for (int m = 1; m <= 8; m <<= 1) v += __shfl_xor(v, m);
            if (lrow == 0)
                E1p[(size_t)slot * NTOT + panel * 64 + r * 16 + quad * 4 + g] = v;
        }
    }
}

// 32 blocks x 256: per-row closed form. div = sum(32 slots) - exp2(sii2).
// sum_j log1p(-P_ij) ~= -1  (sum_j P_ij == 1 exactly; S2/2 ~ 1e-4 dropped).
// Device-scope done-counter: last-finishing block writes the output
// (R9/R10-proven; only 32 blocks -> fence cost negligible).
__global__ void rowterm_kernel(const float* __restrict__ E1p, const float* __restrict__ spos,
                               const float* __restrict__ sii2, float* __restrict__ acc,
                               unsigned int* __restrict__ done, float* __restrict__ out) {
    int i = blockIdx.x * 256 + threadIdx.x;
    float div = 0.f;
#pragma unroll
    for (int s = 0; s < 32; ++s) div += E1p[(size_t)s * NTOT + i];
    div -= __builtin_amdgcn_exp2f(sii2[i]);
    float sp = spos[i];
    float pmt = __expf(sp) / div;
    float term = sp - __logf(div) - 1.0f - __logf(1.0f - pmt);

    term = wave_sum64(term);
    __shared__ float red[4];
    if ((threadIdx.x & 63) == 0) red[threadIdx.x >> 6] = term;
    __syncthreads();
    if (threadIdx.x == 0) {
        atomicAdd(acc, red[0] + red[1] + red[2] + red[3]);
        __threadfence();
        unsigned int prev = atomicAdd(done, 1u);
        if (prev == 31u) {   // last block: atomic read-back, single write
            float total = atomicAdd(acc, 0.0f);
            out[0] = -total * (1.0f / (float)NTOT);
        }
    }
}

extern "C" void kernel_launch(void* const* d_in, const int* in_sizes, int n_in,
                              void* d_out, int out_size, void* d_ws, size_t ws_size,
                              hipStream_t stream) {
    const float* f1 = (const float*)d_in[0];
    const float* f2 = (const float*)d_in[1];
    float* out = (float*)d_out;

    char* ws = (char*)d_ws;
    unsigned char* xs = (unsigned char*)ws;                   // 1 MB packed fp8
    float* E1p  = (float*)(ws + (size_t)NTOT * D);            // 32*8192 f32 = 1 MB
    float* spos = E1p + 32 * NTOT;                            // 8192 f32
    float* sii2 = spos + NTOT;                                // 8192 f32
    float* acc  = sii2 + NTOT;                                // 1 f32
    unsigned int* done = (unsigned int*)(acc + 1);            // 1 u32

    cast_pos_kernel<<<1024, 256, 0, stream>>>(f1, f2, xs, spos, sii2, acc, done);
    gram_kernel<<<dim3(8, 128), 256, 0, stream>>>(xs, E1p);
    rowterm_kernel<<<32, 256, 0, stream>>>(E1p, spos, sii2, acc, done, out);
}

// Round 16
// 79.746 us; speedup vs baseline: 1.3505x; 1.3505x over previous
//
#include <hip/hip_runtime.h>
#include <hip/hip_bf16.h>
#include <hip/hip_fp8.h>

#define HALF 4096
#define NTOT 8192
#define D 128
#define KS2 3.79828256f   // sqrt(10*log2(e)); acc = s_ij*log2(e), e = exp2(acc)

typedef __attribute__((ext_vector_type(4))) float f32x4;

__device__ __forceinline__ float wave_sum64(float v) {
#pragma unroll
    for (int m = 32; m >= 1; m >>= 1) v += __shfl_xor(v, m);
    return v;
}

// One wave per pair b. Writes x*KS2 as fp8 e4m3 in MFMA-fragment-packed layout:
// byte offset g*2048 + k*512 + (quad*16+lrow)*8 + j <-> X[g*16+lrow][k*32+quad*8+j]
// (R11-proven). Also: spos[b] (exact fp32 positive dot), sii2[row] = log2-scaled
// self-sim from the SAME fp8-rounded values (exact diagonal cancellation), and
// zero-init of the acc/done counters used by rowterm.
__global__ void cast_pos_kernel(const float* __restrict__ f1, const float* __restrict__ f2,
                                unsigned char* __restrict__ xs, float* __restrict__ spos,
                                float* __restrict__ sii2, float* __restrict__ acc,
                                unsigned int* __restrict__ done) {
    if (blockIdx.x == 0 && threadIdx.x == 0) { *acc = 0.f; *done = 0u; }

    int w = (blockIdx.x * blockDim.x + threadIdx.x) >> 6;   // pair index b, 0..4095
    int l = threadIdx.x & 63;
    float2 a1 = ((const float2*)(f1 + (size_t)w * D))[l];
    float2 a2 = ((const float2*)(f2 + (size_t)w * D))[l];

    __hip_fp8_e4m3 q1x(a1.x * KS2), q1y(a1.y * KS2);
    __hip_fp8_e4m3 q2x(a2.x * KS2), q2y(a2.y * KS2);

    // this thread covers X[w][2l..2l+2): k = l>>4, quad = (l>>2)&3, j = (l&3)*2
    int g = w >> 4, lrow = w & 15;
    int k = l >> 4, quad = (l >> 2) & 3, j = (l & 3) * 2;
    size_t off = (size_t)g * 2048 + k * 512 + (quad * 16 + lrow) * 8 + j;
    *(unsigned short*)(xs + off) =
        (unsigned short)(q1x.__x | ((unsigned short)q1y.__x << 8));
    *(unsigned short*)(xs + off + 256 * 2048) =
        (unsigned short)(q2x.__x | ((unsigned short)q2y.__x << 8));

    // self-sim from the SAME fp8-rounded values (cancels vs MFMA diagonal)
    float b1x = (float)q1x, b1y = (float)q1y;
    float b2x = (float)q2x, b2y = (float)q2y;
    float s1 = b1x * b1x + b1y * b1y;
    float s2 = b2x * b2x + b2y * b2y;
    float d  = a1.x * a2.x + a1.y * a2.y;
    s1 = wave_sum64(s1); s2 = wave_sum64(s2); d = wave_sum64(d);
    if (l == 0) {
        sii2[w] = s1; sii2[w + HALF] = s2;
        float sp = d * 10.0f;
        spos[w] = sp; spos[w + HALF] = sp;
    }
}

// LDS-free, fence-free, atomic-free Gram row-sum sweep on packed fp8 operands
// (1 MB -> L2-resident). Grid 1024 = 8 slabs x 128 panels = exactly 4
// blocks/CU, single perfectly-balanced round (fp8 halves af regs -> fits the
// 128-reg cap at 4/CU; 64 VGPR + 32 AGPR measured, clean). Block: rows
// panel*64..+63, cols slab*1024..+1023 over 8 tile-steps; wave = 64 rows x
// 32 cols/step. Rotated pipeline: MFMA consumes bfr, next tile's loads
// re-issue into the SAME regs (WAR-safe), exp2 block overlaps the L2 latency.
// tt loop stays rolled (full unroll => spill, R5). Single buffer only:
// two-buffer variants spill at this cap regardless of coding style (R14/R15).
// Plain disjoint-slot stores (R11: fences/atomics in the gram tail poison L2).
__global__ __launch_bounds__(256, 4) void gram_kernel(const unsigned char* __restrict__ xs,
                                                      float* __restrict__ E1p) {
    const int slab = blockIdx.x;    // 0..7
    const int panel = blockIdx.y;   // 0..127
    const int t = threadIdx.x;
    const int wave = t >> 6, lane = t & 63;
    const int lrow = lane & 15, quad = lane >> 4;

    // A fragments: row group g = panel*4 + r; byte off g*2048 + k*512 + lane*8
    const unsigned char* ab = xs + (size_t)panel * 4 * 2048 + lane * 8;
    long af[4][4];
#pragma unroll
    for (int k = 0; k < 4; ++k)
#pragma unroll
        for (int r = 0; r < 4; ++r)
            af[k][r] = *(const long*)(ab + r * 2048 + k * 512);

    // B base: col group = slab*64 + tt*8 + wave*2 + c (2048 B per group)
    const unsigned char* bb = xs + ((size_t)slab * 64 + wave * 2) * 2048 + lane * 8;
    long bfr[4][2];
#pragma unroll
    for (int k = 0; k < 4; ++k)
#pragma unroll
        for (int c = 0; c < 2; ++c)
            bfr[k][c] = *(const long*)(bb + c * 2048 + k * 512);

    f32x4 rs4[4];
#pragma unroll
    for (int r = 0; r < 4; ++r) rs4[r] = (f32x4){0.f, 0.f, 0.f, 0.f};

#pragma unroll 1
    for (int tt = 0; tt < 8; ++tt) {
        f32x4 a2[4][2];
#pragma unroll
        for (int r = 0; r < 4; ++r)
#pragma unroll
            for (int c = 0; c < 2; ++c) a2[r][c] = (f32x4){0.f, 0.f, 0.f, 0.f};
#pragma unroll
        for (int k = 0; k < 4; ++k)
#pragma unroll
            for (int r = 0; r < 4; ++r)
#pragma unroll
                for (int c = 0; c < 2; ++c)
                    a2[r][c] = __builtin_amdgcn_mfma_f32_16x16x32_fp8_fp8(af[k][r], bfr[k][c], a2[r][c], 0, 0, 0);

        if (tt < 7) {   // rotate: next tile's loads into the same regs
            const unsigned char* bn = bb + (size_t)(tt + 1) * 8 * 2048;
#pragma unroll
            for (int k = 0; k < 4; ++k)
#pragma unroll
                for (int c = 0; c < 2; ++c)
                    bfr[k][c] = *(const long*)(bn + c * 2048 + k * 512);
        }

#pragma unroll
        for (int r = 0; r < 4; ++r)
#pragma unroll
            for (int c = 0; c < 2; ++c)
#pragma unroll
                for (int g = 0; g < 4; ++g)
                    rs4[r][g] += __builtin_amdgcn_exp2f(a2[r][c][g]);
    }

    // reduce over the 16 lanes sharing a quad; disjoint-slot store (no atomics)
    const int slot = slab * 4 + wave;   // 0..31
#pragma unroll
    for (int r = 0; r < 4; ++r) {
#pragma unroll
        for (int g = 0; g < 4; ++g) {
            float v = rs4[r][g];
#pragma unroll
            for (int m = 1; m <= 8; m <<= 1) v += __shfl_xor(v, m);
            if (lrow == 0)
                E1p[(size_t)slot * NTOT + panel * 64 + r * 16 + quad * 4 + g] = v;
        }
    }
}

// 32 blocks x 256: per-row closed form. div = sum(32 slots) - exp2(sii2).
// sum_j log1p(-P_ij) ~= -1  (sum_j P_ij == 1 exactly; S2/2 ~ 1e-4 dropped).
// Device-scope done-counter: last-finishing block writes the output
// (R9/R10-proven; only 32 blocks -> fence cost negligible).
__global__ void rowterm_kernel(const float* __restrict__ E1p, const float* __restrict__ spos,
                               const float* __restrict__ sii2, float* __restrict__ acc,
                               unsigned int* __restrict__ done, float* __restrict__ out) {
    int i = blockIdx.x * 256 + threadIdx.x;
    float div = 0.f;
#pragma unroll
    for (int s = 0; s < 32; ++s) div += E1p[(size_t)s * NTOT + i];
    div -= __builtin_amdgcn_exp2f(sii2[i]);
    float sp = spos[i];
    float pmt = __expf(sp) / div;
    float term = sp - __logf(div) - 1.0f - __logf(1.0f - pmt);

    term = wave_sum64(term);
    __shared__ float red[4];
    if ((threadIdx.x & 63) == 0) red[threadIdx.x >> 6] = term;
    __syncthreads();
    if (threadIdx.x == 0) {
        atomicAdd(acc, red[0] + red[1] + red[2] + red[3]);
        __threadfence();
        unsigned int prev = atomicAdd(done, 1u);
        if (prev == 31u) {   // last block: atomic read-back, single write
            float total = atomicAdd(acc, 0.0f);
            out[0] = -total * (1.0f / (float)NTOT);
        }
    }
}

extern "C" void kernel_launch(void* const* d_in, const int* in_sizes, int n_in,
                              void* d_out, int out_size, void* d_ws, size_t ws_size,
                              hipStream_t stream) {
    const float* f1 = (const float*)d_in[0];
    const float* f2 = (const float*)d_in[1];
    float* out = (float*)d_out;

    char* ws = (char*)d_ws;
    unsigned char* xs = (unsigned char*)ws;                   // 1 MB packed fp8
    float* E1p  = (float*)(ws + (size_t)NTOT * D);            // 32*8192 f32 = 1 MB
    float* spos = E1p + 32 * NTOT;                            // 8192 f32
    float* sii2 = spos + NTOT;                                // 8192 f32
    float* acc  = sii2 + NTOT;                                // 1 f32
    unsigned int* done = (unsigned int*)(acc + 1);            // 1 u32

    cast_pos_kernel<<<1024, 256, 0, stream>>>(f1, f2, xs, spos, sii2, acc, done);
    gram_kernel<<<dim3(8, 128), 256, 0, stream>>>(xs, E1p);
    rowterm_kernel<<<32, 256, 0, stream>>>(E1p, spos, sii2, acc, done, out);
}